// Round 5
// baseline (270.505 us; speedup 1.0000x reference)
//
#include <hip/hip_runtime.h>
#include <math.h>

#define NODE_DIM 64
#define EDGE_DIM 16
#define HEADS 4
#define CAP 64
#define NEG_SLOPE 0.2f
#define BN_EPS 1e-5f

typedef unsigned short ushort_t;

__device__ __forceinline__ float wave_max64(float v) {
#pragma unroll
    for (int o = 32; o; o >>= 1) v = fmaxf(v, __shfl_xor(v, o, 64));
    return v;
}
__device__ __forceinline__ float wave_sum64(float v) {
#pragma unroll
    for (int o = 32; o; o >>= 1) v += __shfl_xor(v, o, 64);
    return v;
}
__device__ __forceinline__ float lrelu(float s) {
    return fmaxf(s, 0.f) + NEG_SLOPE * fminf(s, 0.f);
}
__device__ __forceinline__ ushort_t f2bf(float f) {  // round-to-nearest-even
    unsigned int b = __float_as_uint(f);
    b += 0x7FFFu + ((b >> 16) & 1u);
    return (ushort_t)(b >> 16);
}
__device__ __forceinline__ float bf2f(ushort_t u) {
    return __uint_as_float(((unsigned int)u) << 16);
}

// K1: xr = x@Wr + br (f32) ; xlbf = bf16(x@Wl + bl). One wave per row.
__global__ __launch_bounds__(256) void k_transform(
    const float* __restrict__ x, const float* __restrict__ Wl,
    const float* __restrict__ bl, const float* __restrict__ Wr,
    const float* __restrict__ br, ushort_t* __restrict__ xlbf,
    float* __restrict__ xr, int n)
{
    __shared__ float sWl[NODE_DIM * NODE_DIM];
    __shared__ float sWr[NODE_DIM * NODE_DIM];
    for (int i = threadIdx.x; i < NODE_DIM * NODE_DIM; i += 256) {
        sWl[i] = Wl[i];
        sWr[i] = Wr[i];
    }
    __syncthreads();
    int lane = threadIdx.x & 63;
    int wid = threadIdx.x >> 6;
    for (int row = blockIdx.x * 4 + wid; row < n; row += gridDim.x * 4) {
        float xown = x[(size_t)row * NODE_DIM + lane];
        float al = bl[lane], ar = br[lane];
#pragma unroll
        for (int k = 0; k < NODE_DIM; k++) {
            float xv = __shfl(xown, k, 64);
            al = fmaf(xv, sWl[k * 64 + lane], al);
            ar = fmaf(xv, sWr[k * 64 + lane], ar);
        }
        xlbf[(size_t)row * NODE_DIM + lane] = f2bf(al);
        xr[(size_t)row * NODE_DIM + lane] = ar;
    }
}

// K2: bucket edges by dst; store (src, eid) packed. cursors end as degree.
__global__ __launch_bounds__(256) void k_scatter(
    const int* __restrict__ ei, int* __restrict__ cursors,
    int2* __restrict__ slot2, int E)
{
    int e = blockIdx.x * 256 + threadIdx.x;
    if (e >= E) return;
    int src = ei[e];
    int dst = ei[E + e];
    int pos = atomicAdd(&cursors[dst], 1);
    if (pos < CAP) slot2[(size_t)dst * CAP + pos] = make_int2(src, e);
}

struct Pipe {
    float4 e0, e1, e2, e3;
    ushort_t xu;
};

// K3 (fused): 4 nodes per block, one wave each. No __syncthreads (per-wave LDS).
// Phase A: lane = channel, 2-deep pipelined loop over edges.
// Phase B: lane = edge, wave softmax. Phase C: lane = channel, pipelined re-gather.
__global__ __launch_bounds__(256) void k_fused(
    const int2* __restrict__ slot2, const int* __restrict__ cursors,
    const float* __restrict__ eattr, const float* __restrict__ We,
    const float* __restrict__ att, const ushort_t* __restrict__ xlbf,
    const float* __restrict__ xr, const float* __restrict__ bias,
    float* __restrict__ out, int n)
{
    __shared__ float slog[4][CAP * 4];    // per-wave logits [t][head]
    __shared__ float salpha[4][CAP * 4];  // per-wave alpha  [t][head]

    int wid = threadIdx.x >> 6;
    int lane = threadIdx.x & 63;
    int i = blockIdx.x * 4 + wid;
    if (i >= n) return;

    int deg = cursors[i];
    if (deg > CAP) deg = CAP;
    bool act = (lane < deg);

    int2 se = act ? slot2[(size_t)i * CAP + lane] : make_int2(0, 0);
    int se_x = se.x, se_y = se.y;

    // per-lane channel constants
    float xr_c = xr[(size_t)i * NODE_DIM + lane];
    float att_c = att[lane];
    float we_c[EDGE_DIM];
#pragma unroll
    for (int k = 0; k < EDGE_DIM; k++) we_c[k] = We[k * NODE_DIM + lane];

    int h = lane >> 4;
    float* slogW = slog[wid];
    float* salW = salpha[wid];

    auto LOADP = [&](int T, Pipe& P) {
        int src_t = __builtin_amdgcn_readlane(se_x, T);
        int eid_t = __builtin_amdgcn_readlane(se_y, T);
        const float4* e4 = (const float4*)(eattr + (size_t)eid_t * EDGE_DIM);
        P.e0 = e4[0]; P.e1 = e4[1]; P.e2 = e4[2]; P.e3 = e4[3];
        P.xu = xlbf[(size_t)src_t * NODE_DIM + lane];
    };
    auto COMP = [&](int T, const Pipe& P) {
        float p = 0.f;
        p = fmaf(P.e0.x, we_c[0], p);  p = fmaf(P.e0.y, we_c[1], p);
        p = fmaf(P.e0.z, we_c[2], p);  p = fmaf(P.e0.w, we_c[3], p);
        p = fmaf(P.e1.x, we_c[4], p);  p = fmaf(P.e1.y, we_c[5], p);
        p = fmaf(P.e1.z, we_c[6], p);  p = fmaf(P.e1.w, we_c[7], p);
        p = fmaf(P.e2.x, we_c[8], p);  p = fmaf(P.e2.y, we_c[9], p);
        p = fmaf(P.e2.z, we_c[10], p); p = fmaf(P.e2.w, we_c[11], p);
        p = fmaf(P.e3.x, we_c[12], p); p = fmaf(P.e3.y, we_c[13], p);
        p = fmaf(P.e3.z, we_c[14], p); p = fmaf(P.e3.w, we_c[15], p);
        float s = bf2f(P.xu) + xr_c + p;
        float g = lrelu(s) * att_c;
        g += __shfl_xor(g, 1, 64);
        g += __shfl_xor(g, 2, 64);
        g += __shfl_xor(g, 4, 64);
        g += __shfl_xor(g, 8, 64);
        if ((lane & 15) == 0) slogW[T * 4 + h] = g;
    };

    // ---- Phase A: 2-deep software pipeline over edges ----
    {
        Pipe PA, PB;
        if (deg > 0) {
            LOADP(0, PA);
            int t = 0;
            for (;;) {
                if (t + 1 < deg) LOADP(t + 1, PB);
                COMP(t, PA);
                t++;
                if (t >= deg) break;
                if (t + 1 < deg) LOADP(t + 1, PA);
                COMP(t, PB);
                t++;
                if (t >= deg) break;
            }
        }
    }

    // ---- Phase B: lane = edge; wave softmax over deg lanes, 4 heads ----
    float4 lg = ((const float4*)slogW)[lane];
    float l0 = act ? lg.x : -1e30f;
    float l1 = act ? lg.y : -1e30f;
    float l2 = act ? lg.z : -1e30f;
    float l3 = act ? lg.w : -1e30f;
    float m0 = wave_max64(l0), m1 = wave_max64(l1);
    float m2 = wave_max64(l2), m3 = wave_max64(l3);
    float e0 = act ? __expf(l0 - m0) : 0.f;
    float e1 = act ? __expf(l1 - m1) : 0.f;
    float e2 = act ? __expf(l2 - m2) : 0.f;
    float e3 = act ? __expf(l3 - m3) : 0.f;
    float s0 = wave_sum64(e0), s1 = wave_sum64(e1);
    float s2 = wave_sum64(e2), s3 = wave_sum64(e3);
    ((float4*)salW)[lane] = make_float4(
        e0 / (s0 + 1e-16f), e1 / (s1 + 1e-16f),
        e2 / (s2 + 1e-16f), e3 / (s3 + 1e-16f));

    // ---- Phase C: lane = channel; pipelined re-gather + aggregate ----
    float acc0 = 0.f, acc1 = 0.f;
    {
        ushort_t cxA = 0, cxB = 0;
        auto CLOADA = [&](int T) {
            int src_t = __builtin_amdgcn_readlane(se_x, T);
            cxA = xlbf[(size_t)src_t * NODE_DIM + lane];
        };
        auto CLOADB = [&](int T) {
            int src_t = __builtin_amdgcn_readlane(se_x, T);
            cxB = xlbf[(size_t)src_t * NODE_DIM + lane];
        };
        if (deg > 0) {
            CLOADA(0);
            int t = 0;
            for (;;) {
                if (t + 1 < deg) CLOADB(t + 1);
                acc0 = fmaf(salW[t * 4 + h], bf2f(cxA), acc0);
                t++;
                if (t >= deg) break;
                if (t + 1 < deg) CLOADA(t + 1);
                acc1 = fmaf(salW[t * 4 + h], bf2f(cxB), acc1);
                t++;
                if (t >= deg) break;
            }
        }
    }
    out[(size_t)i * NODE_DIM + lane] = acc0 + acc1 + bias[lane];
}

// K4: column sums / sumsq for BatchNorm
__global__ __launch_bounds__(256) void k_bnstat(
    const float* __restrict__ out, float* __restrict__ stats, int n)
{
    __shared__ float sbuf[256];
    int col = threadIdx.x & 63;
    int rgrp = threadIdx.x >> 6;
    float s = 0.f, q = 0.f;
    for (int row = blockIdx.x * 4 + rgrp; row < n; row += gridDim.x * 4) {
        float v = out[(size_t)row * 64 + col];
        s += v;
        q = fmaf(v, v, q);
    }
    sbuf[threadIdx.x] = s;
    __syncthreads();
    if (threadIdx.x < 64) {
        s = sbuf[threadIdx.x] + sbuf[threadIdx.x + 64] +
            sbuf[threadIdx.x + 128] + sbuf[threadIdx.x + 192];
        atomicAdd(&stats[col], s);
    }
    __syncthreads();
    sbuf[threadIdx.x] = q;
    __syncthreads();
    if (threadIdx.x < 64) {
        q = sbuf[threadIdx.x] + sbuf[threadIdx.x + 64] +
            sbuf[threadIdx.x + 128] + sbuf[threadIdx.x + 192];
        atomicAdd(&stats[64 + col], q);
    }
}

// K5: BN normalize + residual + exact GELU, in place on d_out
__global__ __launch_bounds__(256) void k_final(
    float* __restrict__ out, const float* __restrict__ x,
    const float* __restrict__ stats, const float* __restrict__ gamma,
    const float* __restrict__ beta, int total, float invn)
{
    int i = blockIdx.x * 256 + threadIdx.x;
    if (i >= total) return;
    int c = i & 63;
    float mean = stats[c] * invn;
    float var = stats[64 + c] * invn - mean * mean;
    float z = (out[i] - mean) * rsqrtf(var + BN_EPS) * gamma[c] + beta[c] + x[i];
    out[i] = z * 0.5f * (1.f + erff(z * 0.70710678118654752f));
}

extern "C" void kernel_launch(void* const* d_in, const int* in_sizes, int n_in,
                              void* d_out, int out_size, void* d_ws, size_t ws_size,
                              hipStream_t stream)
{
    const float* x     = (const float*)d_in[0];
    const int*   ei    = (const int*)d_in[1];
    const float* eattr = (const float*)d_in[2];
    const float* Wl    = (const float*)d_in[3];
    const float* bl    = (const float*)d_in[4];
    const float* Wr    = (const float*)d_in[5];
    const float* br    = (const float*)d_in[6];
    const float* We    = (const float*)d_in[7];
    const float* att   = (const float*)d_in[8];
    const float* bias  = (const float*)d_in[9];
    const float* gamma = (const float*)d_in[10];
    const float* beta  = (const float*)d_in[11];
    int n = in_sizes[0] / NODE_DIM;
    int E = in_sizes[1] / 2;

    char* ws = (char*)d_ws;
    float*    xr     = (float*)ws;    ws += (size_t)n * NODE_DIM * 4;
    ushort_t* xlbf   = (ushort_t*)ws; ws += (size_t)n * NODE_DIM * 2;
    int2*     slot2  = (int2*)ws;     ws += (size_t)n * CAP * 8;
    int*      cursors= (int*)ws;      ws += (size_t)n * 4;
    float*    stats  = (float*)ws;    ws += 128 * 4;

    // zero cursors + stats (contiguous)
    hipMemsetAsync(cursors, 0, (size_t)(n + 128) * 4, stream);

    k_transform<<<512, 256, 0, stream>>>(x, Wl, bl, Wr, br, xlbf, xr, n);
    k_scatter<<<(E + 255) / 256, 256, 0, stream>>>(ei, cursors, slot2, E);
    k_fused<<<(n + 3) / 4, 256, 0, stream>>>(slot2, cursors, eattr, We, att,
                                             xlbf, xr, bias, (float*)d_out, n);
    k_bnstat<<<256, 256, 0, stream>>>((const float*)d_out, stats, n);
    k_final<<<(n * NODE_DIM + 255) / 256, 256, 0, stream>>>(
        (float*)d_out, x, stats, gamma, beta, n * NODE_DIM, 1.0f / n);
}